// Round 8
// baseline (287.814 us; speedup 1.0000x reference)
//
#include <hip/hip_runtime.h>

// PointPillarScatter3d on MI355X (gfx950)
// NZ=1, NY=NX=512, C=128, B=4, P=320000.
// Strategy: scatter->gather inversion, BARRIER-FREE wave-private tiles.
//   hipMemsetAsync: map[B*CELLS] = -1
//   k_scatter_idx:  map[b*CELLS + cell] = point index (cells unique per batch)
//   k_gather:       each WAVE independently processes 16-cell tiles (grid-stride).
//     - 16 point indices in registers (lane<16 loads map), distributed via __shfl
//       -> feat loads have no LDS dependency.
//     - Phase B: 8 passes x (2 rows/pass), full 512B row per 32 lanes, f4 loads;
//       ds_write_b128 into wave-private [16][33] f4 slab -> conflict-free.
//     - Phase C: 8 store instrs, 16 channels x 64B granule-exact segments;
//       scalar LDS reads 2-way aliased = free (m136).
//     - ZERO __syncthreads: intra-wave waitcnts only; waves/tiles overlap freely,
//       no block-wide vmcnt drain (the m97 structural stall).
//   Full output covered -> zeros from LDS for empty cells, no separate zero pass.

#define NXD 512
#define NYD 512
#define NZD 1
#define CB  128
#define CELLS (NXD * NYD * NZD)   // 262144

#define TPW  16                   // cells per wave-tile
#define NTHR 256                  // 4 waves/block

typedef float f4 __attribute__((ext_vector_type(4)));

__global__ void k_scatter_idx(const int* __restrict__ coords,
                              int* __restrict__ map, int P) {
    int p = blockIdx.x * blockDim.x + threadIdx.x;
    if (p >= P) return;
    int4 c = ((const int4*)coords)[p];      // (b, z, y, x)
    int cell = c.y * (NYD * NXD) + c.z * NXD + c.w;
    map[c.x * CELLS + cell] = p;
}

__global__ __launch_bounds__(NTHR) void k_gather(const float* __restrict__ feat,
                                                 const int* __restrict__ map,
                                                 float* __restrict__ out,
                                                 int ntiles) {
    __shared__ f4 lds4[4][TPW * 33];        // 33 f4/cell pad; 33,792 B/block -> 4 blk/CU

    const int lane = threadIdx.x & 63;
    const int w    = threadIdx.x >> 6;
    f4* __restrict__ L = lds4[w];
    const float* __restrict__ Lf = (const float*)L;

    const int gw     = blockIdx.x * 4 + w;  // global wave id
    const int nwaves = gridDim.x * 4;

    const int hi  = lane >> 5;              // phase B: row parity
    const int c4  = lane & 31;              // phase B: f4 column within row
    const int ch0 = lane >> 2;              // phase C: channel 0..15
    const int x4  = lane & 3;               // phase C: f4 index along 16 cells

    for (int tile = gw; tile < ntiles; tile += nwaves) {
        const int b         = tile / (CELLS / TPW);
        const int cell_base = (tile % (CELLS / TPW)) * TPW;

        int idx0 = -1;
        if (lane < TPW) idx0 = map[b * CELLS + cell_base + lane];

        // Phase B: 2 rows per pass, 8 passes -> 16 rows. All 8 loads independent.
        #pragma unroll
        for (int rr = 0; rr < 8; ++rr) {
            const int row = rr * 2 + hi;
            const int idx = __shfl(idx0, row);
            f4 v = (f4)(0.f);
            if (idx >= 0) v = ((const f4*)feat)[(size_t)idx * (CB / 4) + c4];
            L[row * 33 + c4] = v;           // ds_write_b128, conflict-free
        }

        // Phase C: per instr 16 channels x 64B contiguous segments; 8 instrs.
        float* outb = out + (size_t)b * CB * CELLS + cell_base + x4 * 4;
        #pragma unroll
        for (int cc = 0; cc < 8; ++cc) {
            const int c = cc * 16 + ch0;
            f4 v;
            v.x = Lf[(x4 * 4 + 0) * 132 + c];
            v.y = Lf[(x4 * 4 + 1) * 132 + c];
            v.z = Lf[(x4 * 4 + 2) * 132 + c];
            v.w = Lf[(x4 * 4 + 3) * 132 + c];
            *(f4*)(outb + (size_t)c * CELLS) = v;
        }
    }
}

extern "C" void kernel_launch(void* const* d_in, const int* in_sizes, int n_in,
                              void* d_out, int out_size, void* d_ws, size_t ws_size,
                              hipStream_t stream) {
    const float* feat   = (const float*)d_in[1];
    const int*   coords = (const int*)d_in[2];
    float*       out    = (float*)d_out;
    int*         map    = (int*)d_ws;   // B*CELLS int32 = 4 MB

    const int B = out_size / (CB * CELLS);
    const int P = in_sizes[1] / CB;
    const int n_map  = B * CELLS;
    const int ntiles = B * (CELLS / TPW);   // 65536

    (void)hipMemsetAsync(map, 0xFF, (size_t)n_map * sizeof(int), stream);
    k_scatter_idx<<<(P + 255) / 256, 256, 0, stream>>>(coords, map, P);
    k_gather<<<2048, NTHR, 0, stream>>>(feat, map, out, ntiles);
}

// Round 9
// 184.181 us; speedup vs baseline: 1.5627x; 1.5627x over previous
//
#include <hip/hip_runtime.h>

// PointPillarScatter3d on MI355X (gfx950)
// NZ=1, NY=NX=512, C=128, B=4, P=320000.
// Strategy: scatter->gather inversion.
//   hipMemsetAsync: map[B*CELLS] = -1
//   k_scatter_idx:  map[b*CELLS + cell] = point index (cells unique per batch)
//   k_gather:       256-cell tile x all 128 channels, 1024 threads, 2 barriers.
//     Phase B: full 512B row gathers (32 lanes x float4/row, 32 rows per pass,
//              8 passes), scalar LDS writes (4-way aliasing, proven non-critical).
//     Phase C: per channel, ONE wave instr = 64 lanes x 16B = 1KB contiguous run
//              (4x R1's 256B, 2x R6's 512B), 16 channels/pass, 8 passes.
//   LDS: f4 ldsC[128][64] slot-swizzled (slot = x4 ^ ((c>>2)&7)) -> phase-C
//        ds_read_b128 conflict-free. 128KB -> 1 block/CU, 16 waves/CU.
//   Full output covered -> zeros from LDS for empty cells, no separate zero pass.

#define NXD 512
#define NYD 512
#define NZD 1
#define CB  128
#define CELLS (NXD * NYD * NZD)   // 262144

#define TILE 256                  // cells per block
#define NTHR 1024                 // 16 waves; 1 block/CU = 16 waves/CU

typedef float f4 __attribute__((ext_vector_type(4)));

__global__ void k_scatter_idx(const int* __restrict__ coords,
                              int* __restrict__ map, int P) {
    int p = blockIdx.x * blockDim.x + threadIdx.x;
    if (p >= P) return;
    int4 c = ((const int4*)coords)[p];      // (b, z, y, x)
    int cell = c.y * (NYD * NXD) + c.z * NXD + c.w;
    map[c.x * CELLS + cell] = p;
}

__global__ __launch_bounds__(NTHR) void k_gather(const float* __restrict__ feat,
                                                 const int* __restrict__ map,
                                                 float* __restrict__ out) {
    __shared__ int pidx[TILE];
    __shared__ f4  ldsC[CB][TILE / 4];      // [channel][x-slot], swizzled; 128 KB

    const int t = threadIdx.x;
    const int tiles_per_b = CELLS / TILE;   // 1024
    const int b = blockIdx.x / tiles_per_b;
    const int cell_base = (blockIdx.x % tiles_per_b) * TILE;

    if (t < TILE) pidx[t] = map[b * CELLS + cell_base + t];
    __syncthreads();

    // Phase B: 32 lanes x float4 = one 512B row; 32 rows in flight, 8 passes.
    {
        const int c4 = t & 31;     // float4 column within row (channels 4c4..4c4+3)
        const int r0 = t >> 5;     // 0..31
        int idxr[8];
        #pragma unroll
        for (int rr = 0; rr < 8; ++rr) idxr[rr] = pidx[rr * 32 + r0];
        #pragma unroll
        for (int rr = 0; rr < 8; ++rr) {
            const int x = rr * 32 + r0;
            f4 v = (f4)(0.f);
            if (idxr[rr] >= 0)
                v = ((const f4*)feat)[(size_t)idxr[rr] * (CB / 4) + c4];
            const int slot = (x >> 2) ^ (c4 & 7);   // stays within aligned 8-group
            const int xe   = x & 3;
            ((float*)&ldsC[c4 * 4 + 0][(x >> 2) ^ (((c4 * 4 + 0) >> 2) & 7)])[xe] = v.x;
            ((float*)&ldsC[c4 * 4 + 1][(x >> 2) ^ (((c4 * 4 + 1) >> 2) & 7)])[xe] = v.y;
            ((float*)&ldsC[c4 * 4 + 2][(x >> 2) ^ (((c4 * 4 + 2) >> 2) & 7)])[xe] = v.z;
            ((float*)&ldsC[c4 * 4 + 3][(x >> 2) ^ (((c4 * 4 + 3) >> 2) & 7)])[xe] = v.w;
            (void)slot;
        }
    }
    __syncthreads();

    // Phase C: per channel, one conflict-free b128 read + 64 lanes x float4
    // = 1KB contiguous store. 16 channels in flight, 8 passes.
    {
        const int x4 = t & 63;     // float4 index along 256 cells (uniform wave: same c)
        const int cr = t >> 6;     // 0..15
        float* outb = out + (size_t)b * CB * CELLS + cell_base;
        #pragma unroll
        for (int cc = 0; cc < 8; ++cc) {
            const int c = cc * 16 + cr;
            f4 v = ldsC[c][x4 ^ ((c >> 2) & 7)];
            *reinterpret_cast<f4*>(outb + (size_t)c * CELLS + x4 * 4) = v;
        }
    }
}

extern "C" void kernel_launch(void* const* d_in, const int* in_sizes, int n_in,
                              void* d_out, int out_size, void* d_ws, size_t ws_size,
                              hipStream_t stream) {
    const float* feat   = (const float*)d_in[1];
    const int*   coords = (const int*)d_in[2];
    float*       out    = (float*)d_out;
    int*         map    = (int*)d_ws;   // B*CELLS int32 = 4 MB

    const int B = out_size / (CB * CELLS);
    const int P = in_sizes[1] / CB;
    const int n_map = B * CELLS;

    (void)hipMemsetAsync(map, 0xFF, (size_t)n_map * sizeof(int), stream);
    k_scatter_idx<<<(P + 255) / 256, 256, 0, stream>>>(coords, map, P);
    k_gather<<<B * (CELLS / TILE), NTHR, 0, stream>>>(feat, map, out);
}